// Round 1
// baseline (266.087 us; speedup 1.0000x reference)
//
#include <hip/hip_runtime.h>
#include <hip/hip_bf16.h>
#include <math.h>

// Problem constants (from reference): B=4, H=16, L=4096, D=64, S=128
constexpr int BB = 4;
constexpr int HH = 16;
constexpr int LL = 4096;
constexpr int DD = 64;
constexpr int SS = 128;

// rows total = B*H*L = 262144; one thread per row; 256 threads/block -> 1024 blocks.
// All rows in one block share the same (b,h) since 256 | L.

__global__ __launch_bounds__(256) void quantizer_kernel(
    const float* __restrict__ x,   // [B,H,L,D]
    const float* __restrict__ c,   // [H,S,D]
    float* __restrict__ out,       // [B,H,L,S] one-hot
    float* __restrict__ out_c)     // [H,S,D] copy of c
{
    const int tid = threadIdx.x;
    const int blk = blockIdx.x;
    const long long row0 = (long long)blk * 256;
    const long long r = row0 + tid;

    // h index is uniform per block: (row0 / L) % H
    const int h = (int)((row0 >> 12) & (HH - 1));
    const float* __restrict__ chead = c + (size_t)h * SS * DD;

    // ---- load x row into registers (16 coalesced float4 loads) ----
    float xr[DD];
    const float4* __restrict__ xp = (const float4*)(x + (size_t)r * DD);
    #pragma unroll
    for (int i = 0; i < DD / 4; ++i) {
        float4 v = xp[i];
        xr[4 * i + 0] = v.x;
        xr[4 * i + 1] = v.y;
        xr[4 * i + 2] = v.z;
        xr[4 * i + 3] = v.w;
    }

    // ---- 128 dot products; codebook reads are wave-uniform (scalar loads) ----
    float best = -INFINITY;
    int bidx = 0;
    #pragma unroll 2
    for (int s = 0; s < SS; ++s) {
        const float* __restrict__ cs = chead + s * DD;
        float a0 = 0.f, a1 = 0.f, a2 = 0.f, a3 = 0.f;
        #pragma unroll
        for (int d = 0; d < DD; d += 4) {
            a0 = fmaf(xr[d + 0], cs[d + 0], a0);
            a1 = fmaf(xr[d + 1], cs[d + 1], a1);
            a2 = fmaf(xr[d + 2], cs[d + 2], a2);
            a3 = fmaf(xr[d + 3], cs[d + 3], a3);
        }
        float dot = (a0 + a1) + (a2 + a3);
        // strict > keeps the FIRST max index (np.argmax tie semantics)
        if (dot > best) { best = dot; bidx = s; }
    }

    // ---- share argmaxes, then cooperatively write one-hot (coalesced) ----
    __shared__ int amax[256];
    amax[tid] = bidx;
    __syncthreads();

    // Block owns rows [row0, row0+256): 256*128 floats = 8192 float4s.
    float4* __restrict__ op = (float4*)(out + (size_t)row0 * SS);
    #pragma unroll 4
    for (int i = tid; i < 8192; i += 256) {
        const int rr = i >> 5;          // row within block (32 float4 per row)
        const int s0 = (i & 31) * 4;    // first s covered by this float4
        const int am = amax[rr];
        float4 v;
        v.x = (s0 + 0 == am) ? 1.f : 0.f;
        v.y = (s0 + 1 == am) ? 1.f : 0.f;
        v.z = (s0 + 2 == am) ? 1.f : 0.f;
        v.w = (s0 + 3 == am) ? 1.f : 0.f;
        op[i] = v;
    }

    // ---- copy c to second output region (first 128 blocks, one float4 each thread) ----
    // H*S*D = 131072 floats = 32768 float4s = 128 blocks * 256 threads * 1
    if (blk < 128) {
        const float4* __restrict__ src = (const float4*)c;
        float4* __restrict__ dst = (float4*)out_c;
        const int idx = blk * 256 + tid;
        dst[idx] = src[idx];
    }
}

extern "C" void kernel_launch(void* const* d_in, const int* in_sizes, int n_in,
                              void* d_out, int out_size, void* d_ws, size_t ws_size,
                              hipStream_t stream) {
    const float* x = (const float*)d_in[0];   // [B,H,L,D] fp32
    const float* c = (const float*)d_in[1];   // [H,S,D]   fp32
    float* out = (float*)d_out;               // onehot [B,H,L,S] then c [H,S,D]
    float* out_c = out + (size_t)BB * HH * LL * SS;

    const int rows = BB * HH * LL;            // 262144
    const int blocks = rows / 256;            // 1024
    quantizer_kernel<<<blocks, 256, 0, stream>>>(x, c, out, out_c);
}

// Round 2
// 248.230 us; speedup vs baseline: 1.0719x; 1.0719x over previous
//
#include <hip/hip_runtime.h>
#include <hip/hip_bf16.h>
#include <math.h>

// Problem constants (from reference): B=4, H=16, L=4096, D=64, S=128
constexpr int BB = 4;
constexpr int HH = 16;
constexpr int LL = 4096;
constexpr int DD = 64;
constexpr int SS = 128;

// One thread per row; 256 threads/block -> 1024 blocks.
// All rows in a block share the same (b,h) since 256 | L.
// Codebook head (128x64 fp32 = 32 KiB) staged in LDS: ds_read returns
// in-order -> fine-grained lgkmcnt pipelining under the FMA stream
// (SMEM s_load is out-of-order and forces lgkmcnt(0) serialization).

__global__ __launch_bounds__(256) void quantizer_kernel(
    const float* __restrict__ x,   // [B,H,L,D]
    const float* __restrict__ c,   // [H,S,D]
    float* __restrict__ out,       // [B,H,L,S] one-hot
    float* __restrict__ out_c)     // [H,S,D] copy of c
{
    const int tid = threadIdx.x;
    const int blk = blockIdx.x;
    const long long row0 = (long long)blk * 256;
    const long long r = row0 + tid;

    // h index is uniform per block: (row0 / L) % H
    const int h = (int)((row0 >> 12) & (HH - 1));
    const float* __restrict__ chead = c + (size_t)h * SS * DD;

    // ---- stage codebook head into LDS (32 KiB, 8 float4 per thread) ----
    __shared__ float4 cb[SS * DD / 4];           // 2048 float4
    {
        const float4* __restrict__ csrc = (const float4*)chead;
        #pragma unroll
        for (int i = 0; i < 8; ++i)
            cb[tid + i * 256] = csrc[tid + i * 256];
    }

    // ---- load x row into registers (16 coalesced float4 loads) ----
    float xr[DD];
    const float4* __restrict__ xp = (const float4*)(x + (size_t)r * DD);
    #pragma unroll
    for (int i = 0; i < DD / 4; ++i) {
        float4 v = xp[i];
        xr[4 * i + 0] = v.x;
        xr[4 * i + 1] = v.y;
        xr[4 * i + 2] = v.z;
        xr[4 * i + 3] = v.w;
    }

    __syncthreads();

    // ---- 128 dot products from LDS (broadcast reads, conflict-free) ----
    float best = -INFINITY;
    int bidx = 0;
    #pragma unroll 4
    for (int s = 0; s < SS; ++s) {
        const float4* __restrict__ crow = &cb[s * (DD / 4)];
        float a0 = 0.f, a1 = 0.f, a2 = 0.f, a3 = 0.f;
        #pragma unroll
        for (int d4 = 0; d4 < DD / 4; ++d4) {
            float4 cv = crow[d4];
            a0 = fmaf(xr[4 * d4 + 0], cv.x, a0);
            a1 = fmaf(xr[4 * d4 + 1], cv.y, a1);
            a2 = fmaf(xr[4 * d4 + 2], cv.z, a2);
            a3 = fmaf(xr[4 * d4 + 3], cv.w, a3);
        }
        float dot = (a0 + a1) + (a2 + a3);
        // strict > keeps the FIRST max index (np.argmax tie semantics)
        if (dot > best) { best = dot; bidx = s; }
    }

    // ---- share argmaxes, then cooperatively write one-hot (coalesced) ----
    __shared__ int amax[256];
    amax[tid] = bidx;
    __syncthreads();

    // Block owns rows [row0, row0+256): 256*128 floats = 8192 float4s.
    float4* __restrict__ op = (float4*)(out + (size_t)row0 * SS);
    #pragma unroll 4
    for (int i = tid; i < 8192; i += 256) {
        const int rr = i >> 5;          // row within block (32 float4 per row)
        const int s0 = (i & 31) * 4;    // first s covered by this float4
        const int am = amax[rr];
        float4 v;
        v.x = (s0 + 0 == am) ? 1.f : 0.f;
        v.y = (s0 + 1 == am) ? 1.f : 0.f;
        v.z = (s0 + 2 == am) ? 1.f : 0.f;
        v.w = (s0 + 3 == am) ? 1.f : 0.f;
        op[i] = v;
    }

    // ---- copy c to second output region (first 128 blocks) ----
    // H*S*D = 131072 floats = 32768 float4s = 128 blocks * 256 threads
    if (blk < 128) {
        const float4* __restrict__ src = (const float4*)c;
        float4* __restrict__ dst = (float4*)out_c;
        const int idx = blk * 256 + tid;
        dst[idx] = src[idx];
    }
}

extern "C" void kernel_launch(void* const* d_in, const int* in_sizes, int n_in,
                              void* d_out, int out_size, void* d_ws, size_t ws_size,
                              hipStream_t stream) {
    const float* x = (const float*)d_in[0];   // [B,H,L,D] fp32
    const float* c = (const float*)d_in[1];   // [H,S,D]   fp32
    float* out = (float*)d_out;               // onehot [B,H,L,S] then c [H,S,D]
    float* out_c = out + (size_t)BB * HH * LL * SS;

    const int rows = BB * HH * LL;            // 262144
    const int blocks = rows / 256;            // 1024
    quantizer_kernel<<<blocks, 256, 0, stream>>>(x, c, out, out_c);
}